// Round 1
// baseline (236.335 us; speedup 1.0000x reference)
//
#include <hip/hip_runtime.h>
#include <hip/hip_bf16.h>
#include <stdint.h>

#define M_NODES 100000
#define E_EDGES 500000
#define NCOL    512      // U(256) | V(256)
#define HID     256

typedef unsigned short u16;
typedef u16   u16x8 __attribute__((ext_vector_type(8)));
typedef u16   u16x4 __attribute__((ext_vector_type(4)));
typedef __bf16 bf16x8 __attribute__((ext_vector_type(8)));
typedef float f32x4 __attribute__((ext_vector_type(4)));

static __device__ __forceinline__ u16 f2bf(float f) {
  uint32_t u = __float_as_uint(f);
  u += 0x7fff + ((u >> 16) & 1);      // RNE
  return (u16)(u >> 16);
}
static __device__ __forceinline__ float bf2f(u16 h) {
  return __uint_as_float(((uint32_t)h) << 16);
}

// ---------------- kernel 1: latent fp32 -> bf16 ----------------
__global__ __launch_bounds__(256) void k_convert(const float* __restrict__ in,
                                                 u16* __restrict__ out, int n4) {
  int i = blockIdx.x * blockDim.x + threadIdx.x;
  int stride = gridDim.x * blockDim.x;
  for (; i < n4; i += stride) {
    float4 f = reinterpret_cast<const float4*>(in)[i];
    u16x4 o;
    o[0] = f2bf(f.x); o[1] = f2bf(f.y); o[2] = f2bf(f.z); o[3] = f2bf(f.w);
    reinterpret_cast<u16x4*>(out)[i] = o;
  }
}

// ---------------- kernel 2: build Bt [512][128] bf16 ----------------
// Bt[j][k] = (j<256) ? W1[j][k] : W1[j-256][128+k]
__global__ __launch_bounds__(256) void k_weights(const float* __restrict__ W1,
                                                 u16* __restrict__ Bt) {
  int idx = blockIdx.x * 256 + threadIdx.x;   // 0..65535
  int j = idx >> 7, k = idx & 127;
  float w = (j < HID) ? W1[j * 256 + k] : W1[(j - HID) * 256 + 128 + k];
  Bt[idx] = f2bf(w);
}

// ---------------- kernel 3: GEMM  UV[m][n] = A[m][:] . Bt[n][:]  (+b1 for n<256)
// A: [100000][128] bf16, Bt: [512][128] bf16, UV: [100000][512] bf16
// 128x128 tile, 4 waves, each wave 64x64 via 4x4 of mfma_f32_16x16x32_bf16.
__global__ __launch_bounds__(256, 2) void k_gemm(const u16* __restrict__ A,
                                                 const u16* __restrict__ Bt,
                                                 const float* __restrict__ b1,
                                                 u16* __restrict__ UV) {
  __shared__ __align__(16) u16 ldsA[128 * 128];
  __shared__ __align__(16) u16 ldsB[128 * 128];
  const int t = threadIdx.x;
  const int bm = blockIdx.x, bn = blockIdx.y;

  // stage: row-major [128][16 slots of 8 bf16], slot XOR-swizzled by (row&7)
  {
    const int sub = t >> 4;      // 0..15
    const int slot = t & 15;
    #pragma unroll
    for (int r = 0; r < 8; ++r) {
      int row = r * 16 + sub;
      int sw = (slot ^ (row & 7)) * 8;
      int grow = bm * 128 + row; if (grow > M_NODES - 1) grow = M_NODES - 1;
      u16x8 va = *reinterpret_cast<const u16x8*>(A + (size_t)grow * 128 + slot * 8);
      *reinterpret_cast<u16x8*>(&ldsA[row * 128 + sw]) = va;
      int brow = bn * 128 + row;   // always < 512
      u16x8 vb = *reinterpret_cast<const u16x8*>(Bt + (size_t)brow * 128 + slot * 8);
      *reinterpret_cast<u16x8*>(&ldsB[row * 128 + sw]) = vb;
    }
  }
  __syncthreads();

  const int w  = t >> 6;           // wave 0..3
  const int l  = t & 63;
  const int wm = (w >> 1) * 64;
  const int wn = (w & 1) * 64;
  const int lr = l & 15;
  const int lk = l >> 4;           // 0..3

  f32x4 acc[4][4];                 // [nt][mt]
  #pragma unroll
  for (int i = 0; i < 4; ++i)
    #pragma unroll
    for (int j = 0; j < 4; ++j) acc[i][j] = f32x4{0.f, 0.f, 0.f, 0.f};

  #pragma unroll
  for (int kk = 0; kk < 128; kk += 32) {
    const int s = (kk >> 3) + lk;  // 16B slot index
    bf16x8 fa[4], fb[4];
    #pragma unroll
    for (int mt = 0; mt < 4; ++mt) {
      int row = wm + mt * 16 + lr;
      fa[mt] = *reinterpret_cast<const bf16x8*>(&ldsA[row * 128 + ((s ^ (row & 7)) * 8)]);
    }
    #pragma unroll
    for (int nt = 0; nt < 4; ++nt) {
      int row = wn + nt * 16 + lr;
      fb[nt] = *reinterpret_cast<const bf16x8*>(&ldsB[row * 128 + ((s ^ (row & 7)) * 8)]);
    }
    #pragma unroll
    for (int nt = 0; nt < 4; ++nt)
      #pragma unroll
      for (int mt = 0; mt < 4; ++mt)
        acc[nt][mt] = __builtin_amdgcn_mfma_f32_16x16x32_bf16(fb[nt], fa[mt], acc[nt][mt], 0, 0, 0);
  }

  // D[n][m]: lane l, reg r -> n_local = (l>>4)*4 + r, m_local = l&15
  #pragma unroll
  for (int nt = 0; nt < 4; ++nt) {
    #pragma unroll
    for (int mt = 0; mt < 4; ++mt) {
      int mg = bm * 128 + wm + mt * 16 + lr;
      int ng = bn * 128 + wn + nt * 16 + lk * 4;
      if (mg < M_NODES) {
        u16x4 o;
        #pragma unroll
        for (int r = 0; r < 4; ++r) {
          float v = acc[nt][mt][r];
          int col = ng + r;
          if (col < HID) v += b1[col];     // fold b1 into U half
          o[r] = f2bf(v);
        }
        *reinterpret_cast<u16x4*>(&UV[(size_t)mg * NCOL + ng]) = o;
      }
    }
  }
}

// ---------------- kernel 4: per-edge  sigmoid(W2 . relu(U[s]+V[d]) + b2) -----
// half-wave (32 lanes) per edge; lane hl covers hidden j = hl*8 .. hl*8+7
__global__ __launch_bounds__(256) void k_edge(const u16* __restrict__ UV,
                                              const int* __restrict__ src,
                                              const int* __restrict__ dst,
                                              const float* __restrict__ W2,
                                              const float* __restrict__ b2p,
                                              float* __restrict__ out) {
  const int t = threadIdx.x;
  const int hl = t & 31;
  const int hw = blockIdx.x * 8 + (t >> 5);
  const int nhw = gridDim.x * 8;

  float w2r[8];
  #pragma unroll
  for (int i = 0; i < 8; ++i) w2r[i] = W2[hl * 8 + i];
  const float b2 = *b2p;

  for (int e = hw; e < E_EDGES; e += nhw) {
    int s = src[e];
    int d = dst[e];
    u16x8 uu = *reinterpret_cast<const u16x8*>(UV + (size_t)s * NCOL + hl * 8);
    u16x8 vv = *reinterpret_cast<const u16x8*>(UV + (size_t)d * NCOL + HID + hl * 8);
    float a = 0.f;
    #pragma unroll
    for (int i = 0; i < 8; ++i) {
      float h = bf2f(uu[i]) + bf2f(vv[i]);
      h = fmaxf(h, 0.f);
      a = fmaf(h, w2r[i], a);
    }
    a += __shfl_xor(a, 16, 64);
    a += __shfl_xor(a, 8, 64);
    a += __shfl_xor(a, 4, 64);
    a += __shfl_xor(a, 2, 64);
    a += __shfl_xor(a, 1, 64);
    if (hl == 0) {
      out[e] = 1.0f / (1.0f + __expf(-(a + b2)));
    }
  }
}

extern "C" void kernel_launch(void* const* d_in, const int* in_sizes, int n_in,
                              void* d_out, int out_size, void* d_ws, size_t ws_size,
                              hipStream_t stream) {
  const float* latent = (const float*)d_in[0];   // [100000*128]
  const float* W1     = (const float*)d_in[1];   // [256*256]
  const float* b1     = (const float*)d_in[2];   // [256]
  const float* W2     = (const float*)d_in[3];   // [256]
  const float* b2     = (const float*)d_in[4];   // [1]
  const int*   eidx   = (const int*)d_in[5];     // [2*500000]

  char* ws = (char*)d_ws;
  u16* latent_bf = (u16*)ws;                             // 25,600,000 B
  u16* Btw       = (u16*)(ws + 25600000);                // 131,072 B
  u16* UV        = (u16*)(ws + 25600000 + 131072);       // 102,400,000 B

  k_convert<<<2048, 256, 0, stream>>>(latent, latent_bf, (M_NODES * 128) / 4);
  k_weights<<<256, 256, 0, stream>>>(W1, Btw);
  dim3 gg((M_NODES + 127) / 128, NCOL / 128);
  k_gemm<<<gg, 256, 0, stream>>>(latent_bf, Btw, b1, UV);
  k_edge<<<1024, 256, 0, stream>>>(UV, eidx, eidx + E_EDGES, W2, b2, (float*)d_out);
}

// Round 2
// 233.177 us; speedup vs baseline: 1.0135x; 1.0135x over previous
//
#include <hip/hip_runtime.h>
#include <hip/hip_bf16.h>
#include <stdint.h>

#define M_NODES 100000
#define E_EDGES 500000
#define NCOL    512      // U(256) | V(256)
#define HID     256

typedef unsigned short u16;
typedef u16   u16x8 __attribute__((ext_vector_type(8)));
typedef u16   u16x4 __attribute__((ext_vector_type(4)));
typedef __bf16 bf16x8 __attribute__((ext_vector_type(8)));
typedef float f32x4 __attribute__((ext_vector_type(4)));

static __device__ __forceinline__ u16 f2bf(float f) {
  uint32_t u = __float_as_uint(f);
  u += 0x7fff + ((u >> 16) & 1);      // RNE
  return (u16)(u >> 16);
}
static __device__ __forceinline__ float bf2f(u16 h) {
  return __uint_as_float(((uint32_t)h) << 16);
}

// async global->LDS, 16B per lane; LDS dest must be wave-uniform base (lane*16 implicit)
#define GLOAD_LDS16(g, lds)                                                          \
  __builtin_amdgcn_global_load_lds(                                                  \
      (const __attribute__((address_space(1))) uint32_t*)(g),                        \
      (__attribute__((address_space(3))) uint32_t*)(lds), 16, 0, 0)

// ---------------- kernel 1: latent fp32 -> bf16 (linear row-major) ----------------
__global__ __launch_bounds__(256) void k_convert(const float* __restrict__ in,
                                                 u16* __restrict__ out, int n4) {
  int i = blockIdx.x * blockDim.x + threadIdx.x;
  int stride = gridDim.x * blockDim.x;
  for (; i < n4; i += stride) {
    float4 f = reinterpret_cast<const float4*>(in)[i];
    u16x4 o;
    o[0] = f2bf(f.x); o[1] = f2bf(f.y); o[2] = f2bf(f.z); o[3] = f2bf(f.w);
    reinterpret_cast<u16x4*>(out)[i] = o;
  }
}

// ---------------- kernel 2: build Bt [512][128] bf16, PRE-SWIZZLED ----------------
// storage slot s (8 bf16 each) of row j holds logical slot ls = s ^ (j&7), so that
// linear global_load_lds staging lands in LDS exactly in the XOR-swizzled layout
// the compute phase's ds_read expects.
// logical: Bt[j][k] = (j<256) ? W1[j][k] : W1[j-256][128+k]
__global__ __launch_bounds__(256) void k_weights(const float* __restrict__ W1,
                                                 u16* __restrict__ Bt) {
  int idx = blockIdx.x * 256 + threadIdx.x;   // 0..65535
  int j = idx >> 7, kk = idx & 127;
  int s = kk >> 3, i = kk & 7;
  int ls = s ^ (j & 7);
  int k = ls * 8 + i;
  float w = (j < HID) ? W1[j * 256 + k] : W1[(j - HID) * 256 + 128 + k];
  Bt[idx] = f2bf(w);
}

// ---------------- kernel 3: GEMM  UV[m][n] = A[m][:] . Bt[n][:]  (+b1 for n<256)
// A: [100000][128] bf16 (linear), Bt: [512][128] bf16 (pre-swizzled), UV bf16.
// 128x128 tile, 4 waves, 64x64/wave via 4x4 of mfma_f32_16x16x32_bf16.
// Staging via global_load_lds: A's per-lane SOURCE address is inverse-swizzled
// (linear LDS dest), B's source is linear because Bt is pre-swizzled in global.
__global__ __launch_bounds__(256, 2) void k_gemm(const u16* __restrict__ A,
                                                 const u16* __restrict__ Bt,
                                                 const float* __restrict__ b1,
                                                 u16* __restrict__ UV) {
  __shared__ __align__(16) u16 ldsA[128 * 128];
  __shared__ __align__(16) u16 ldsB[128 * 128];
  const int t = threadIdx.x;
  const int bm = blockIdx.x, bn = blockIdx.y;
  const int w = t >> 6, l = t & 63;

  // ---- async stage: each wave issues 8 chunks of 1KB for A and for B ----
  {
    const int lr4 = l >> 4;       // row within 4-row chunk
    const int ls  = l & 15;       // 16B slot within row
    #pragma unroll
    for (int c = 0; c < 8; ++c) {
      const int chunk = w * 8 + c;           // 0..31
      const int row   = chunk * 4 + lr4;     // 0..127
      int grow = bm * 128 + row;
      if (grow >= M_NODES) grow = M_NODES - 1;
      const int gslot = ls ^ (row & 7);      // inverse swizzle on the source
      GLOAD_LDS16(A + (size_t)grow * 128 + gslot * 8, &ldsA[chunk * 512]);
      // B: pre-swizzled storage -> purely linear, perfectly coalesced
      GLOAD_LDS16(Bt + (size_t)bn * 16384 + chunk * 512 + l * 8, &ldsB[chunk * 512]);
    }
  }
  __syncthreads();

  const int wm = (w >> 1) * 64;
  const int wn = (w & 1) * 64;
  const int lr = l & 15;
  const int lk = l >> 4;           // 0..3

  f32x4 acc[4][4];                 // [nt][mt]
  #pragma unroll
  for (int i = 0; i < 4; ++i)
    #pragma unroll
    for (int j = 0; j < 4; ++j) acc[i][j] = f32x4{0.f, 0.f, 0.f, 0.f};

  #pragma unroll
  for (int kk = 0; kk < 128; kk += 32) {
    const int s = (kk >> 3) + lk;  // 16B slot index
    bf16x8 fa[4], fb[4];
    #pragma unroll
    for (int mt = 0; mt < 4; ++mt) {
      int row = wm + mt * 16 + lr;
      fa[mt] = *reinterpret_cast<const bf16x8*>(&ldsA[row * 128 + ((s ^ (row & 7)) * 8)]);
    }
    #pragma unroll
    for (int nt = 0; nt < 4; ++nt) {
      int row = wn + nt * 16 + lr;
      fb[nt] = *reinterpret_cast<const bf16x8*>(&ldsB[row * 128 + ((s ^ (row & 7)) * 8)]);
    }
    #pragma unroll
    for (int nt = 0; nt < 4; ++nt)
      #pragma unroll
      for (int mt = 0; mt < 4; ++mt)
        acc[nt][mt] = __builtin_amdgcn_mfma_f32_16x16x32_bf16(fb[nt], fa[mt], acc[nt][mt], 0, 0, 0);
  }

  // D[n][m]: lane l, reg r -> n_local = (l>>4)*4 + r, m_local = l&15
  #pragma unroll
  for (int nt = 0; nt < 4; ++nt) {
    #pragma unroll
    for (int mt = 0; mt < 4; ++mt) {
      int mg = bm * 128 + wm + mt * 16 + lr;
      int ng = bn * 128 + wn + nt * 16 + lk * 4;
      if (mg < M_NODES) {
        u16x4 o;
        #pragma unroll
        for (int r = 0; r < 4; ++r) {
          float v = acc[nt][mt][r];
          int col = ng + r;
          if (col < HID) v += b1[col];     // fold b1 into U half
          o[r] = f2bf(v);
        }
        *reinterpret_cast<u16x4*>(&UV[(size_t)mg * NCOL + ng]) = o;
      }
    }
  }
}

// ---------------- kernel 4: per-edge  sigmoid(W2 . relu(U[s]+V[d]) + b2) -----
// 16 lanes per edge (lane sub covers hidden j = sub*16 .. sub*16+15);
// wave = 4 edges/iter; 4x16B loads in flight per lane; VGPR<=64 for full occupancy.
__global__ __launch_bounds__(256, 8) void k_edge(const u16* __restrict__ UV,
                                                 const int* __restrict__ src,
                                                 const int* __restrict__ dst,
                                                 const float* __restrict__ W2,
                                                 const float* __restrict__ b2p,
                                                 float* __restrict__ out) {
  const int t = threadIdx.x;
  const int l = t & 63;
  const int sub = l & 15;          // lane within edge group
  const int eg = l >> 4;           // edge slot 0..3 in wave
  const int wid = blockIdx.x * 4 + (t >> 6);
  const int nw = gridDim.x * 4;

  float w2r[16];
  #pragma unroll
  for (int i = 0; i < 16; ++i) w2r[i] = W2[sub * 16 + i];
  const float b2 = *b2p;

  // E_EDGES % 4 == 0, so edges e..e+3 are all valid whenever e < E_EDGES
  for (int e = wid * 4; e < E_EDGES; e += nw * 4) {
    const int s = src[e + eg];
    const int d = dst[e + eg];
    const u16* pu = UV + (size_t)s * NCOL + sub * 16;
    const u16* pv = UV + (size_t)d * NCOL + HID + sub * 16;
    u16x8 ua = *reinterpret_cast<const u16x8*>(pu);
    u16x8 ub = *reinterpret_cast<const u16x8*>(pu + 8);
    u16x8 va = *reinterpret_cast<const u16x8*>(pv);
    u16x8 vb = *reinterpret_cast<const u16x8*>(pv + 8);
    float a = 0.f;
    #pragma unroll
    for (int i = 0; i < 8; ++i) {
      float h = bf2f(ua[i]) + bf2f(va[i]);
      h = fmaxf(h, 0.f);
      a = fmaf(h, w2r[i], a);
    }
    #pragma unroll
    for (int i = 0; i < 8; ++i) {
      float h = bf2f(ub[i]) + bf2f(vb[i]);
      h = fmaxf(h, 0.f);
      a = fmaf(h, w2r[8 + i], a);
    }
    a += __shfl_xor(a, 1, 64);
    a += __shfl_xor(a, 2, 64);
    a += __shfl_xor(a, 4, 64);
    a += __shfl_xor(a, 8, 64);
    if (sub == 0) {
      out[e + eg] = 1.0f / (1.0f + __expf(-(a + b2)));
    }
  }
}

extern "C" void kernel_launch(void* const* d_in, const int* in_sizes, int n_in,
                              void* d_out, int out_size, void* d_ws, size_t ws_size,
                              hipStream_t stream) {
  const float* latent = (const float*)d_in[0];   // [100000*128]
  const float* W1     = (const float*)d_in[1];   // [256*256]
  const float* b1     = (const float*)d_in[2];   // [256]
  const float* W2     = (const float*)d_in[3];   // [256]
  const float* b2     = (const float*)d_in[4];   // [1]
  const int*   eidx   = (const int*)d_in[5];     // [2*500000]

  char* ws = (char*)d_ws;
  u16* latent_bf = (u16*)ws;                             // 25,600,000 B
  u16* Btw       = (u16*)(ws + 25600000);                // 131,072 B
  u16* UV        = (u16*)(ws + 25600000 + 131072);       // 102,400,000 B

  k_convert<<<2048, 256, 0, stream>>>(latent, latent_bf, (M_NODES * 128) / 4);
  k_weights<<<256, 256, 0, stream>>>(W1, Btw);
  dim3 gg((M_NODES + 127) / 128, NCOL / 128);
  k_gemm<<<gg, 256, 0, stream>>>(latent_bf, Btw, b1, UV);
  k_edge<<<2048, 256, 0, stream>>>(UV, eidx, eidx + E_EDGES, W2, b2, (float*)d_out);
}

// Round 5
// 228.686 us; speedup vs baseline: 1.0334x; 1.0196x over previous
//
#include <hip/hip_runtime.h>
#include <hip/hip_bf16.h>
#include <stdint.h>

#define M_NODES 100000
#define E_EDGES 500000
#define NCOL    512      // U(256) | V(256)
#define HID     256

typedef unsigned short u16;
typedef u16   u16x8 __attribute__((ext_vector_type(8)));
typedef u16   u16x4 __attribute__((ext_vector_type(4)));
typedef __bf16 bf16x8 __attribute__((ext_vector_type(8)));
typedef float f32x4 __attribute__((ext_vector_type(4)));

static __device__ __forceinline__ u16 f2bf(float f) {
  uint32_t u = __float_as_uint(f);
  u += 0x7fff + ((u >> 16) & 1);      // RNE
  return (u16)(u >> 16);
}
static __device__ __forceinline__ float bf2f(u16 h) {
  return __uint_as_float(((uint32_t)h) << 16);
}

// ---------------- kernel 1: build Bt [512][128] bf16 (linear) ----------------
// Bt[j][k] = (j<256) ? W1[j][k] : W1[j-256][128+k]
__global__ __launch_bounds__(256) void k_weights(const float* __restrict__ W1,
                                                 u16* __restrict__ Bt) {
  int idx = blockIdx.x * 256 + threadIdx.x;   // 0..65535
  int j = idx >> 7, k = idx & 127;
  float w = (j < HID) ? W1[j * 256 + k] : W1[(j - HID) * 256 + 128 + k];
  Bt[idx] = f2bf(w);
}

// ---------------- kernel 2: fused convert+GEMM -------------------------------
// UV[m][n] = latent[m][:] . Bt[n][:]  (+b1 for n<256), m in [0,100000), n in [0,512)
// Block: 8 waves (512 thr), BM=64 rows x full N=512. Wave w owns cols [w*64,w*64+64).
// B fragments live in VGPRs (loaded straight from L2-resident Bt, once per block).
// A staged fp32->bf16 into 16KB XOR-swizzled LDS. One barrier per block.
__global__ __launch_bounds__(512, 2) void k_gemm(const float* __restrict__ latent,
                                                 const u16* __restrict__ Bt,
                                                 const float* __restrict__ b1,
                                                 u16* __restrict__ UV) {
  __shared__ __align__(16) u16 ldsA[64 * 128];   // 16 KB
  const int t  = threadIdx.x;
  const int w  = t >> 6;          // wave 0..7
  const int l  = t & 63;
  const int lr = l & 15;
  const int lk = l >> 4;          // 0..3
  const int bm = blockIdx.x;      // 64-row tile index

  // ---- B fragments: fb[nt][ks], 16B each, 64 VGPRs total per lane ----
  // logical content: Bt[w*64 + nt*16 + lr][(4*ks+lk)*8 .. +7]
  bf16x8 fb[4][4];
  {
    const u16* bp = Bt + ((size_t)(w * 64 + lr)) * 128 + lk * 8;
    #pragma unroll
    for (int nt = 0; nt < 4; ++nt)
      #pragma unroll
      for (int ks = 0; ks < 4; ++ks)
        fb[nt][ks] = *reinterpret_cast<const bf16x8*>(bp + nt * 16 * 128 + ks * 32);
  }

  // ---- stage A: 64 rows x 128 fp32 -> bf16 LDS, 16B-slot XOR swizzle ----
  {
    const float4* lat4 = reinterpret_cast<const float4*>(latent);
    #pragma unroll
    for (int i = 0; i < 4; ++i) {
      int idx = i * 512 + t;            // 0..2047 over [64 rows][32 f4cols]
      int row = idx >> 5;
      int c4  = idx & 31;
      int grow = bm * 64 + row;
      if (grow >= M_NODES) grow = M_NODES - 1;
      float4 f = lat4[(size_t)grow * 32 + c4];
      u16x4 o;
      o[0] = f2bf(f.x); o[1] = f2bf(f.y); o[2] = f2bf(f.z); o[3] = f2bf(f.w);
      int ss = (c4 >> 1) ^ (row & 7);                 // swizzled 16B slot
      *reinterpret_cast<u16x4*>(&ldsA[row * 128 + ss * 8 + (c4 & 1) * 4]) = o;
    }
  }
  __syncthreads();

  // ---- compute: 64 MFMAs/wave ----
  f32x4 acc[4][4];                 // [nt][mt]
  #pragma unroll
  for (int i = 0; i < 4; ++i)
    #pragma unroll
    for (int j = 0; j < 4; ++j) acc[i][j] = f32x4{0.f, 0.f, 0.f, 0.f};

  #pragma unroll
  for (int ks = 0; ks < 4; ++ks) {
    bf16x8 fa[4];
    #pragma unroll
    for (int mt = 0; mt < 4; ++mt) {
      int row = mt * 16 + lr;
      int ss  = ((4 * ks + lk) ^ (row & 7));
      fa[mt] = *reinterpret_cast<const bf16x8*>(&ldsA[row * 128 + ss * 8]);
    }
    #pragma unroll
    for (int nt = 0; nt < 4; ++nt)
      #pragma unroll
      for (int mt = 0; mt < 4; ++mt)
        acc[nt][mt] = __builtin_amdgcn_mfma_f32_16x16x32_bf16(fb[nt][ks], fa[mt], acc[nt][mt], 0, 0, 0);
  }

  // ---- epilogue: D n-major (n_local = lk*4+r, m_local = lr), u16x4 stores ----
  #pragma unroll
  for (int nt = 0; nt < 4; ++nt) {
    const int ng = w * 64 + nt * 16 + lk * 4;
    float b1v[4] = {0.f, 0.f, 0.f, 0.f};
    if (ng < HID) {
      #pragma unroll
      for (int r = 0; r < 4; ++r) b1v[r] = b1[ng + r];
    }
    #pragma unroll
    for (int mt = 0; mt < 4; ++mt) {
      int mg = bm * 64 + mt * 16 + lr;
      if (mg < M_NODES) {
        u16x4 o;
        #pragma unroll
        for (int r = 0; r < 4; ++r) o[r] = f2bf(acc[nt][mt][r] + b1v[r]);
        *reinterpret_cast<u16x4*>(&UV[(size_t)mg * NCOL + ng]) = o;
      }
    }
  }
}

// ---------------- kernel 3: per-edge  sigmoid(W2 . relu(U[s]+V[d]) + b2) -----
// 16 lanes per edge; wave = 4 edges/iter; unchanged from round 2 (known 74us).
__global__ __launch_bounds__(256, 8) void k_edge(const u16* __restrict__ UV,
                                                 const int* __restrict__ src,
                                                 const int* __restrict__ dst,
                                                 const float* __restrict__ W2,
                                                 const float* __restrict__ b2p,
                                                 float* __restrict__ out) {
  const int t = threadIdx.x;
  const int l = t & 63;
  const int sub = l & 15;          // lane within edge group
  const int eg = l >> 4;           // edge slot 0..3 in wave
  const int wid = blockIdx.x * 4 + (t >> 6);
  const int nw = gridDim.x * 4;

  float w2r[16];
  #pragma unroll
  for (int i = 0; i < 16; ++i) w2r[i] = W2[sub * 16 + i];
  const float b2 = *b2p;

  for (int e = wid * 4; e < E_EDGES; e += nw * 4) {
    const int s = src[e + eg];
    const int d = dst[e + eg];
    const u16* pu = UV + (size_t)s * NCOL + sub * 16;
    const u16* pv = UV + (size_t)d * NCOL + HID + sub * 16;
    u16x8 ua = *reinterpret_cast<const u16x8*>(pu);
    u16x8 ub = *reinterpret_cast<const u16x8*>(pu + 8);
    u16x8 va = *reinterpret_cast<const u16x8*>(pv);
    u16x8 vb = *reinterpret_cast<const u16x8*>(pv + 8);
    float a = 0.f;
    #pragma unroll
    for (int i = 0; i < 8; ++i) {
      float h = bf2f(ua[i]) + bf2f(va[i]);
      h = fmaxf(h, 0.f);
      a = fmaf(h, w2r[i], a);
    }
    #pragma unroll
    for (int i = 0; i < 8; ++i) {
      float h = bf2f(ub[i]) + bf2f(vb[i]);
      h = fmaxf(h, 0.f);
      a = fmaf(h, w2r[8 + i], a);
    }
    a += __shfl_xor(a, 1, 64);
    a += __shfl_xor(a, 2, 64);
    a += __shfl_xor(a, 4, 64);
    a += __shfl_xor(a, 8, 64);
    if (sub == 0) {
      out[e + eg] = 1.0f / (1.0f + __expf(-(a + b2)));
    }
  }
}

extern "C" void kernel_launch(void* const* d_in, const int* in_sizes, int n_in,
                              void* d_out, int out_size, void* d_ws, size_t ws_size,
                              hipStream_t stream) {
  const float* latent = (const float*)d_in[0];   // [100000*128]
  const float* W1     = (const float*)d_in[1];   // [256*256]
  const float* b1     = (const float*)d_in[2];   // [256]
  const float* W2     = (const float*)d_in[3];   // [256]
  const float* b2     = (const float*)d_in[4];   // [1]
  const int*   eidx   = (const int*)d_in[5];     // [2*500000]

  char* ws = (char*)d_ws;
  u16* Btw = (u16*)ws;                 // 131,072 B
  u16* UV  = (u16*)(ws + 131072);      // 102,400,000 B

  k_weights<<<256, 256, 0, stream>>>(W1, Btw);
  k_gemm<<<(M_NODES + 63) / 64, 512, 0, stream>>>(latent, Btw, b1, UV);
  k_edge<<<2048, 256, 0, stream>>>(UV, eidx, eidx + E_EDGES, W2, b2, (float*)d_out);
}

// Round 6
// 208.002 us; speedup vs baseline: 1.1362x; 1.0994x over previous
//
#include <hip/hip_runtime.h>
#include <hip/hip_bf16.h>
#include <stdint.h>

#define M_NODES 100000
#define E_EDGES 500000
#define NCOL    512      // U(256) | V(256)
#define HID     256

typedef unsigned short u16;
typedef u16   u16x8 __attribute__((ext_vector_type(8)));
typedef u16   u16x4 __attribute__((ext_vector_type(4)));
typedef __bf16 bf16x8 __attribute__((ext_vector_type(8)));
typedef float f32x4 __attribute__((ext_vector_type(4)));

static __device__ __forceinline__ u16 f2bf(float f) {
  uint32_t u = __float_as_uint(f);
  u += 0x7fff + ((u >> 16) & 1);      // RNE
  return (u16)(u >> 16);
}
static __device__ __forceinline__ float bf2f(u16 h) {
  return __uint_as_float(((uint32_t)h) << 16);
}

// Column permutation (within each 64-col block): storage s <-> logical n
//   n = nt*16 + lk*4 + r   <->   s = lk*16 + nt*4 + r     (involution)
// UV is stored permuted; k_edge permutes its W2 register load to match.
// U/V halves stay elementwise-aligned (same permutation in every 64-block).
static __device__ __forceinline__ int col_perm(int p) {
  return (p & ~63) + ((p >> 2) & 3) * 16 + ((p >> 4) & 3) * 4 + (p & 3);
}

// ---------------- kernel 1: build Bt [512][128] bf16 (linear) ----------------
// Bt[j][k] = (j<256) ? W1[j][k] : W1[j-256][128+k]
__global__ __launch_bounds__(256) void k_weights(const float* __restrict__ W1,
                                                 u16* __restrict__ Bt) {
  int idx = blockIdx.x * 256 + threadIdx.x;   // 0..65535
  int j = idx >> 7, k = idx & 127;
  float w = (j < HID) ? W1[j * 256 + k] : W1[(j - HID) * 256 + 128 + k];
  Bt[idx] = f2bf(w);
}

// ---------------- kernel 2: fused convert+GEMM -------------------------------
// UV[m][s] = latent[m][:] . Bt[perm(s)][:]  (+b1 for logical col < 256)
// Block: 8 waves (512 thr), BM=64 rows x full N=512. Wave w owns cols [w*64,w*64+64).
// B fragments in VGPRs; A staged fp32->bf16 into 16KB XOR-swizzled LDS; 1 barrier.
// Epilogue: per-lane 16 storage-contiguous values -> 2x u16x8 stores per mt
// (16B chunks, 2 instrs per 128B line -> L2 merges to full-line writebacks).
__global__ __launch_bounds__(512, 2) void k_gemm(const float* __restrict__ latent,
                                                 const u16* __restrict__ Bt,
                                                 const float* __restrict__ b1,
                                                 u16* __restrict__ UV) {
  __shared__ __align__(16) u16 ldsA[64 * 128];   // 16 KB
  const int t  = threadIdx.x;
  const int w  = t >> 6;          // wave 0..7
  const int l  = t & 63;
  const int lr = l & 15;
  const int lk = l >> 4;          // 0..3
  const int bm = blockIdx.x;      // 64-row tile index

  // ---- B fragments: fb[nt][ks], logical col n = w*64 + nt*16 + lr's row of Bt
  bf16x8 fb[4][4];
  {
    const u16* bp = Bt + ((size_t)(w * 64 + lr)) * 128 + lk * 8;
    #pragma unroll
    for (int nt = 0; nt < 4; ++nt)
      #pragma unroll
      for (int ks = 0; ks < 4; ++ks)
        fb[nt][ks] = *reinterpret_cast<const bf16x8*>(bp + nt * 16 * 128 + ks * 32);
  }

  // ---- stage A: 64 rows x 128 fp32 -> bf16 LDS, 16B-slot XOR swizzle ----
  {
    const float4* lat4 = reinterpret_cast<const float4*>(latent);
    #pragma unroll
    for (int i = 0; i < 4; ++i) {
      int idx = i * 512 + t;            // 0..2047 over [64 rows][32 f4cols]
      int row = idx >> 5;
      int c4  = idx & 31;
      int grow = bm * 64 + row;
      if (grow >= M_NODES) grow = M_NODES - 1;
      float4 f = lat4[(size_t)grow * 32 + c4];
      u16x4 o;
      o[0] = f2bf(f.x); o[1] = f2bf(f.y); o[2] = f2bf(f.z); o[3] = f2bf(f.w);
      int ss = (c4 >> 1) ^ (row & 7);                 // swizzled 16B slot
      *reinterpret_cast<u16x4*>(&ldsA[row * 128 + ss * 8 + (c4 & 1) * 4]) = o;
    }
  }
  __syncthreads();

  // ---- compute: 64 MFMAs/wave ----
  f32x4 acc[4][4];                 // [nt][mt]
  #pragma unroll
  for (int i = 0; i < 4; ++i)
    #pragma unroll
    for (int j = 0; j < 4; ++j) acc[i][j] = f32x4{0.f, 0.f, 0.f, 0.f};

  #pragma unroll
  for (int ks = 0; ks < 4; ++ks) {
    bf16x8 fa[4];
    #pragma unroll
    for (int mt = 0; mt < 4; ++mt) {
      int row = mt * 16 + lr;
      int ss  = ((4 * ks + lk) ^ (row & 7));
      fa[mt] = *reinterpret_cast<const bf16x8*>(&ldsA[row * 128 + ss * 8]);
    }
    #pragma unroll
    for (int nt = 0; nt < 4; ++nt)
      #pragma unroll
      for (int mt = 0; mt < 4; ++mt)
        acc[nt][mt] = __builtin_amdgcn_mfma_f32_16x16x32_bf16(fb[nt][ks], fa[mt], acc[nt][mt], 0, 0, 0);
  }

  // ---- epilogue: lane (lr,lk) holds storage cols [w*64+lk*16, +16) of row m ----
  // element e (0..15): nt = e>>2, r = e&3; logical n = w*64 + nt*16 + lk*4 + r
  float b1v[16];
  #pragma unroll
  for (int e = 0; e < 16; ++e) {
    int nt = e >> 2, r = e & 3;
    int n = w * 64 + nt * 16 + lk * 4 + r;       // logical col
    b1v[e] = (n < HID) ? b1[n] : 0.f;
  }
  #pragma unroll
  for (int mt = 0; mt < 4; ++mt) {
    int mg = bm * 64 + mt * 16 + lr;
    if (mg < M_NODES) {
      u16* dst = &UV[(size_t)mg * NCOL + w * 64 + lk * 16];
      u16x8 o0, o1;
      #pragma unroll
      for (int e = 0; e < 8; ++e) {
        int nt = e >> 2, r = e & 3;
        o0[e] = f2bf(acc[nt][mt][r]     + b1v[e]);
        o1[e] = f2bf(acc[nt + 2][mt][r] + b1v[8 + e]);
      }
      *reinterpret_cast<u16x8*>(dst)     = o0;
      *reinterpret_cast<u16x8*>(dst + 8) = o1;
    }
  }
}

// ---------------- kernel 3: per-edge  sigmoid(W2 . relu(U[s]+V[d]) + b2) -----
// 16 lanes per edge; UV columns are stored permuted -> permute W2 load (sum is
// order-invariant; perm is its own inverse). Access pattern unchanged.
__global__ __launch_bounds__(256, 8) void k_edge(const u16* __restrict__ UV,
                                                 const int* __restrict__ src,
                                                 const int* __restrict__ dst,
                                                 const float* __restrict__ W2,
                                                 const float* __restrict__ b2p,
                                                 float* __restrict__ out) {
  const int t = threadIdx.x;
  const int l = t & 63;
  const int sub = l & 15;          // lane within edge group
  const int eg = l >> 4;           // edge slot 0..3 in wave
  const int wid = blockIdx.x * 4 + (t >> 6);
  const int nw = gridDim.x * 4;

  float w2r[16];
  #pragma unroll
  for (int i = 0; i < 16; ++i) w2r[i] = W2[col_perm(sub * 16 + i)];
  const float b2 = *b2p;

  for (int e = wid * 4; e < E_EDGES; e += nw * 4) {
    const int s = src[e + eg];
    const int d = dst[e + eg];
    const u16* pu = UV + (size_t)s * NCOL + sub * 16;
    const u16* pv = UV + (size_t)d * NCOL + HID + sub * 16;
    u16x8 ua = *reinterpret_cast<const u16x8*>(pu);
    u16x8 ub = *reinterpret_cast<const u16x8*>(pu + 8);
    u16x8 va = *reinterpret_cast<const u16x8*>(pv);
    u16x8 vb = *reinterpret_cast<const u16x8*>(pv + 8);
    float a = 0.f;
    #pragma unroll
    for (int i = 0; i < 8; ++i) {
      float h = bf2f(ua[i]) + bf2f(va[i]);
      h = fmaxf(h, 0.f);
      a = fmaf(h, w2r[i], a);
    }
    #pragma unroll
    for (int i = 0; i < 8; ++i) {
      float h = bf2f(ub[i]) + bf2f(vb[i]);
      h = fmaxf(h, 0.f);
      a = fmaf(h, w2r[8 + i], a);
    }
    a += __shfl_xor(a, 1, 64);
    a += __shfl_xor(a, 2, 64);
    a += __shfl_xor(a, 4, 64);
    a += __shfl_xor(a, 8, 64);
    if (sub == 0) {
      out[e + eg] = 1.0f / (1.0f + __expf(-(a + b2)));
    }
  }
}

extern "C" void kernel_launch(void* const* d_in, const int* in_sizes, int n_in,
                              void* d_out, int out_size, void* d_ws, size_t ws_size,
                              hipStream_t stream) {
  const float* latent = (const float*)d_in[0];   // [100000*128]
  const float* W1     = (const float*)d_in[1];   // [256*256]
  const float* b1     = (const float*)d_in[2];   // [256]
  const float* W2     = (const float*)d_in[3];   // [256]
  const float* b2     = (const float*)d_in[4];   // [1]
  const int*   eidx   = (const int*)d_in[5];     // [2*500000]

  char* ws = (char*)d_ws;
  u16* Btw = (u16*)ws;                 // 131,072 B
  u16* UV  = (u16*)(ws + 131072);      // 102,400,000 B

  k_weights<<<256, 256, 0, stream>>>(W1, Btw);
  k_gemm<<<(M_NODES + 63) / 64, 512, 0, stream>>>(latent, Btw, b1, UV);
  k_edge<<<2048, 256, 0, stream>>>(UV, eidx, eidx + E_EDGES, W2, b2, (float*)d_out);
}